// Round 9
// baseline (129.894 us; speedup 1.0000x reference)
//
#include <hip/hip_runtime.h>

typedef float v2f __attribute__((ext_vector_type(2)));

#define W_IMG   128
#define H_IMG   128
#define HW_IMG  16384
#define FX_C    128.0f
#define FY_C    128.0f
#define CX_C    64.0f
#define CY_C    64.0f
#define LOG2E_F 1.4426950408889634f
#define CHUNK   32

// ---------------------------------------------------------------------------
// Inline per-gaussian projection: {px, py, a2, op}, a2 = -0.5/var*log2(e).
// ---------------------------------------------------------------------------
__device__ __forceinline__ float4 proj_of(
    const float* __restrict__ pos, const float* __restrict__ opac,
    const float* __restrict__ scl, const float* __restrict__ qv,
    const float* __restrict__ tv, int i)
{
    float qw = qv[0], qx = qv[1], qy = qv[2], qz = qv[3];
    float qn = sqrtf(qw*qw + qx*qx + qy*qy + qz*qz);
    qw /= qn; qx /= qn; qy /= qn; qz /= qn;

    float R00 = 1.f - 2.f*(qy*qy + qz*qz), R01 = 2.f*(qx*qy - qz*qw), R02 = 2.f*(qx*qz + qy*qw);
    float R10 = 2.f*(qx*qy + qz*qw), R11 = 1.f - 2.f*(qx*qx + qz*qz), R12 = 2.f*(qy*qz - qx*qw);
    float R20 = 2.f*(qx*qz - qy*qw), R21 = 2.f*(qy*qz + qx*qw), R22 = 1.f - 2.f*(qx*qx + qy*qy);

    float x = pos[3*i + 0];
    float y = pos[3*i + 1];
    float z = pos[3*i + 2];

    float cx = R00*x + R01*y + R02*z + tv[0];
    float cy = R10*x + R11*y + R12*z + tv[1];
    float cz = R20*x + R21*y + R22*z + tv[2];

    float px = cx / cz * FX_C + CX_C;
    float py = cy / cz * FY_C + CY_C;

    float s   = scl[i];
    float a2  = (-0.5f / (s * s)) * LOG2E_F;

    float4 r; r.x = px; r.y = py; r.z = a2; r.w = opac[i];
    return r;
}

// ---------------------------------------------------------------------------
// Fused hot kernel. Block = 128x * 16y px, thread tile 2x*4y, 4 waves.
// grid = (8, S). Per 32-gaussian chunk: stage proj + U[32][128] + V[32][16]
// + colors[32] in LDS (~20 KB -> 8 blocks/CU capacity); inner loop is PURE
// ds_read + 20 packed VALU per 8 px.
// NOTE: ALL staging writes use strided loops (e += 256) — round 8's bug was
// an `if (tid < 512)` guard on a 256-thread block leaving half of V unwritten.
// ---------------------------------------------------------------------------
__global__ __launch_bounds__(256, 4) void gemm_fused(
    const float* __restrict__ pos, const float* __restrict__ col,
    const float* __restrict__ opac, const float* __restrict__ scl,
    const float* __restrict__ qv, const float* __restrict__ tv,
    float4* __restrict__ part, int segLen)
{
    __shared__ __align__(16) float  U_lds[CHUNK * 128];  // 16 KB
    __shared__ __align__(16) float  V_lds[CHUNK * 16];   // 2 KB
    __shared__ __align__(16) float  C_lds[CHUNK * 4];    // 512 B
    __shared__ __align__(16) float4 P_lds[CHUNK];        // 512 B

    int tid = threadIdx.x;
    int xt  = tid & 63;                   // x-pair index within the 128-px row
    int wy  = (tid >> 6) * 4;             // wave's y offset within block tile
    int yb  = blockIdx.x * 16;            // block's y base
    int g0  = blockIdx.y * segLen;

    v2f ar0 = 0.f, ag0 = 0.f, ab0 = 0.f, ad0 = 0.f;
    v2f ar1 = 0.f, ag1 = 0.f, ab1 = 0.f, ad1 = 0.f;
    v2f ar2 = 0.f, ag2 = 0.f, ab2 = 0.f, ad2 = 0.f;
    v2f ar3 = 0.f, ag3 = 0.f, ab3 = 0.f, ad3 = 0.f;

    for (int c0 = 0; c0 < segLen; c0 += CHUNK) {
        int cc = (segLen - c0 < CHUNK) ? (segLen - c0) : CHUNK;

        __syncthreads();                           // LDS reuse guard
        if (tid < cc)
            P_lds[tid] = proj_of(pos, opac, scl, qv, tv, g0 + c0 + tid);
        if (tid < cc * 3) {                        // 96 threads: one channel each
            int g = tid / 3, ch = tid - 3 * g;
            C_lds[g * 4 + ch] = col[3 * (g0 + c0 + g) + ch];
        }
        __syncthreads();

        // Stage U: e = g*128 + x; P_lds[e>>7] wave-uniform -> broadcast.
        for (int e = tid; e < cc * 128; e += 256) {
            float4 p = P_lds[e >> 7];
            float dx = (float)(e & 127) - p.x;
            U_lds[e] = p.w * __builtin_amdgcn_exp2f(p.z * dx * dx);
        }
        // Stage V: e = g*16 + y (block-local y). STRIDED: cc*16 = 512 > 256.
        for (int e = tid; e < cc * 16; e += 256) {
            float4 p = P_lds[e >> 4];
            float dy = (float)(yb + (e & 15)) - p.y;
            V_lds[e] = __builtin_amdgcn_exp2f(p.z * dy * dy);
        }
        __syncthreads();

        #pragma unroll 8
        for (int j = 0; j < cc; ++j) {
            v2f    u  = *(const v2f*)(U_lds + j * 128 + 2 * xt);   // ds_read_b64
            float4 v4 = *(const float4*)(V_lds + j * 16 + wy);     // b128 bcast
            float4 c  = *(const float4*)(C_lds + j * 4);           // b128 bcast

            v2f w0 = u * v4.x;
            v2f w1 = u * v4.y;
            v2f w2 = u * v4.z;
            v2f w3 = u * v4.w;

            ar0 += w0 * c.x; ag0 += w0 * c.y; ab0 += w0 * c.z; ad0 += w0;
            ar1 += w1 * c.x; ag1 += w1 * c.y; ab1 += w1 * c.z; ad1 += w1;
            ar2 += w2 * c.x; ag2 += w2 * c.y; ab2 += w2 * c.z; ad2 += w2;
            ar3 += w3 * c.x; ag3 += w3 * c.y; ab3 += w3 * c.z; ad3 += w3;
        }
    }

    size_t segBase = (size_t)blockIdx.y * HW_IMG + 2 * xt;
    {
        size_t b = segBase + (size_t)(yb + wy + 0) * 128;
        float4 o0; o0.x = ar0.x; o0.y = ag0.x; o0.z = ab0.x; o0.w = ad0.x;
        float4 o1; o1.x = ar0.y; o1.y = ag0.y; o1.z = ab0.y; o1.w = ad0.y;
        part[b] = o0; part[b + 1] = o1;
    }
    {
        size_t b = segBase + (size_t)(yb + wy + 1) * 128;
        float4 o0; o0.x = ar1.x; o0.y = ag1.x; o0.z = ab1.x; o0.w = ad1.x;
        float4 o1; o1.x = ar1.y; o1.y = ag1.y; o1.z = ab1.y; o1.w = ad1.y;
        part[b] = o0; part[b + 1] = o1;
    }
    {
        size_t b = segBase + (size_t)(yb + wy + 2) * 128;
        float4 o0; o0.x = ar2.x; o0.y = ag2.x; o0.z = ab2.x; o0.w = ad2.x;
        float4 o1; o1.x = ar2.y; o1.y = ag2.y; o1.z = ab2.y; o1.w = ad2.y;
        part[b] = o0; part[b + 1] = o1;
    }
    {
        size_t b = segBase + (size_t)(yb + wy + 3) * 128;
        float4 o0; o0.x = ar3.x; o0.y = ag3.x; o0.z = ab3.x; o0.w = ad3.x;
        float4 o1; o1.x = ar3.y; o1.y = ag3.y; o1.z = ab3.y; o1.w = ad3.y;
        part[b] = o0; part[b + 1] = o1;
    }
}

// ---------------------------------------------------------------------------
// Fallback hot kernel (tiny-workspace path only): direct 2-D evaluation.
// ---------------------------------------------------------------------------
__global__ __launch_bounds__(256) void render_fb(
    const float* __restrict__ pos, const float* __restrict__ col,
    const float* __restrict__ opac, const float* __restrict__ scl,
    const float* __restrict__ qv, const float* __restrict__ tv,
    float4* __restrict__ part, int segLen)
{
    int p = blockIdx.x * 256 + threadIdx.x;
    float X = (float)(p & (W_IMG - 1));
    float Y = (float)(p >> 7);

    int g0 = blockIdx.y * segLen;
    float nr = 0.f, ng = 0.f, nb = 0.f, den = 0.f;
    for (int j = 0; j < segLen; ++j) {
        int g = g0 + j;
        float4 pg = proj_of(pos, opac, scl, qv, tv, g);
        float dx = X - pg.x;
        float dy = Y - pg.y;
        float d2 = fmaf(dx, dx, dy * dy);
        float e  = pg.w * __builtin_amdgcn_exp2f(pg.z * d2);
        nr  = fmaf(e, col[3*g+0], nr);
        ng  = fmaf(e, col[3*g+1], ng);
        nb  = fmaf(e, col[3*g+2], nb);
        den += e;
    }
    float4 o; o.x = nr; o.y = ng; o.z = nb; o.w = den;
    part[(size_t)blockIdx.y * HW_IMG + p] = o;
}

// ---------------------------------------------------------------------------
// Finalize: reduce segments, add n_chunks*EPS, divide, tiled/transposed fp32
// output: out[t, c, s/tile, s%tile], p = t*step + s, step = tile^2.
// ---------------------------------------------------------------------------
__global__ __launch_bounds__(256) void finalize_kernel(
    const float4* __restrict__ part, float* __restrict__ out,
    const int* __restrict__ chunk_gauss_p, const int* __restrict__ tile_hw_p,
    int N, int nseg)
{
    int p = blockIdx.x * 256 + threadIdx.x;

    float nr = 0.f, ng = 0.f, nb = 0.f, den = 0.f;
    #pragma unroll 8
    for (int s = 0; s < nseg; ++s) {
        float4 v = part[(size_t)s * HW_IMG + p];
        nr += v.x; ng += v.y; nb += v.z; den += v.w;
    }

    int cg = chunk_gauss_p[0];
    int n_chunks = (cg > 0) ? (N / cg) : 0;
    den += (float)n_chunks * 1e-8f;   // EPS added once per scan chunk

    int th   = tile_hw_p[0];
    int step = th * th;
    if (step <= 0 || step > HW_IMG) { th = 64; step = th * th; }
    int t  = p / step;
    int s2 = p - t * step;
    size_t base = (size_t)t * 3 * step + s2;

    out[base]            = nr / den;
    out[base + step]     = ng / den;
    out[base + 2 * step] = nb / den;
}

extern "C" void kernel_launch(void* const* d_in, const int* in_sizes, int n_in,
                              void* d_out, int out_size, void* d_ws, size_t ws_size,
                              hipStream_t stream)
{
    const float* pos  = (const float*)d_in[0];
    const float* col  = (const float*)d_in[1];
    const float* opac = (const float*)d_in[2];
    const float* scl  = (const float*)d_in[3];
    const float* qv   = (const float*)d_in[4];
    const float* tv   = (const float*)d_in[5];
    const int* tile_hw_p     = (const int*)d_in[6];
    const int* chunk_gauss_p = (const int*)d_in[7];

    int N = in_sizes[2];                 // one opacity per gaussian

    // Workspace: only part[S * HW] float4 (factors live in LDS).
    // S=256 -> 2048 blocks = 8 blocks/CU (matches ~20 KB-LDS capacity).
    int S = 0;
    for (int cand = 256; cand >= 8; cand >>= 1) {
        if (N % cand == 0 &&
            (size_t)cand * HW_IMG * 16 <= ws_size) { S = cand; break; }
    }

    float4* part = (float4*)d_ws;

    if (S > 0 && (N / S) % CHUNK == 0) {
        dim3 grid(H_IMG / 16, S);
        gemm_fused<<<grid, 256, 0, stream>>>(
            pos, col, opac, scl, qv, tv, part, N / S);

        finalize_kernel<<<HW_IMG / 256, 256, 0, stream>>>(
            part, (float*)d_out, chunk_gauss_p, tile_hw_p, N, S);
    } else {
        int nseg = 16;
        while (nseg > 1 &&
               ((size_t)nseg * HW_IMG * 16 > ws_size || (N % nseg) != 0))
            nseg >>= 1;

        dim3 grid(HW_IMG / 256, nseg);
        render_fb<<<grid, 256, 0, stream>>>(pos, col, opac, scl, qv, tv, part, N / nseg);

        finalize_kernel<<<HW_IMG / 256, 256, 0, stream>>>(
            part, (float*)d_out, chunk_gauss_p, tile_hw_p, N, nseg);
    }
}